// Round 7
// baseline (3899.794 us; speedup 1.0000x reference)
//
#include <hip/hip_runtime.h>
#include <stdint.h>

// RankingLossL1: negative mining (L1 top-K) + margin ranking loss.
// N=50000 rows, D=128, T=1024 anchors/direction, K=10, GAMMA=1.
//
// Round-7 = round-6 resubmission (r6 hit GPUAcquisitionTimeout, never ran).
// Post-mortem r4/r5: VGPR_Count stuck at ~100 -> the allocator refuses a
// 128-reg resident anchor array and re-materializes it per row (~4x VALU
// bloat). Fix under test:
//   * 2 lanes per anchor: each lane holds a 64-dim HALF (av = 64 VGPRs).
//     Distance = partial |a-g| + __shfl_xor(p,1). Redundant top-k per pair.
//   * 256-thread blocks: 4 waves share one double-buffered 16-row LDS G tile
//     (16KB/block, 4 blocks/CU -> 16 waves/CU). __syncthreads() at loop end =
//     issue-prefetch-early / vmcnt-drain-late.
//   * Two-stage in-place candidate merge (64 -> 8 -> 1 chunks) for 8x merge
//     parallelism, no extra workspace.
//
// Top-k ties: only distance VALUES enter the loss sum, so boundary-tie index
// choices cannot change the scalar result beyond fp rounding.

#define NROWS 50000
#define DDIM  128
#define TT    1024
#define KK    10
#define NCH   64          // N-chunks
#define CH    782         // ceil(NROWS/NCH)
#define TT2   (2 * TT)    // candidate row stride (dir-major anchor slot)
#define TROWS 16          // G rows per LDS tile (8KB; x2 buffers)

typedef float f32x2 __attribute__((ext_vector_type(2)));
typedef float f32x4 __attribute__((ext_vector_type(4)));

__device__ __forceinline__ void topk_insert(float (&val)[KK], int (&idx)[KK],
                                            float cv, int ci) {
  // fully unrolled sorted insert (ascending); static indices -> stays in VGPRs
#pragma unroll
  for (int i = 0; i < KK; i++) {
    const bool lt = cv < val[i];
    const float tv = lt ? val[i] : cv;
    const int ti = lt ? idx[i] : ci;
    val[i] = lt ? cv : val[i];
    idx[i] = lt ? ci : idx[i];
    cv = tv;
    ci = ti;
  }
}

// grid: 2 dirs x 8 tiles(128 anchors) x 64 chunks = 1024 blocks x 256 threads
__global__ __launch_bounds__(256, 4) void mine_kernel(
    const float* __restrict__ out1, const float* __restrict__ out2,
    const int* __restrict__ anc1, const int* __restrict__ anc2,
    float* __restrict__ cand_val, int* __restrict__ cand_idx) {
  const int tid = threadIdx.x;
  const int lane = tid & 63;
  const int w = tid >> 6;  // wave 0..3
  const int bid = blockIdx.x;
  // XCD-aware decode: blocks with equal bid%8 (same XCD under round-robin)
  // share only 8 distinct chunks -> per-XCD G working set 3.2MB < 4MB L2.
  const int chunk = ((bid >> 7) << 3) | (bid & 7);
  const int combo = (bid >> 3) & 15;  // dir*8 + tile
  const int dir = combo >> 3;
  const int tile = combo & 7;

  const float* __restrict__ A = dir ? out2 : out1;
  const float* __restrict__ G = dir ? out1 : out2;
  const int* __restrict__ anc = dir ? anc2 : anc1;

  const int half = lane & 1;               // which 64-dim half this lane owns
  const int a = tile * 128 + w * 32 + (lane >> 1);  // anchor slot [0,1024)
  const int arow = anc[a];

  // 64-dim half of the anchor vector -> 32 f32x2 = 64 VGPRs
  f32x2 av[DDIM / 4];
  {
    const f32x4* ap = (const f32x4*)(A + (size_t)arow * DDIM + half * 64);
#pragma unroll
    for (int j = 0; j < 16; j++) {
      const f32x4 v = ap[j];
      av[2 * j] = (f32x2){v.x, v.y};
      av[2 * j + 1] = (f32x2){v.z, v.w};
    }
  }

  float val[KK];
  int idx[KK];
#pragma unroll
  for (int i = 0; i < KK; i++) {
    val[i] = 3.4e38f;
    idx[i] = 0;
  }

  const int r0 = chunk * CH;
  const int r1 = (r0 + CH < NROWS) ? (r0 + CH) : NROWS;
  const int nt = (r1 - r0 + TROWS - 1) / TROWS;

  // shared double-buffered G tile: 16 rows x 512B = 8KB per buffer
  __shared__ float gt[2][TROWS * DDIM];

  // stage: 256 threads x 2 x 16B; LDS dest base wave-uniform (HW adds lane*16)
  auto STAGE = [&](int b, int rs) {
    const float* src = G + (size_t)rs * DDIM + w * 256 + lane * 4;
    float* dst = &gt[b][w * 256];
#pragma unroll
    for (int c = 0; c < 2; c++) {
      __builtin_amdgcn_global_load_lds(
          (const __attribute__((address_space(1))) uint32_t*)(src + c * 1024),
          (__attribute__((address_space(3))) uint32_t*)(dst + c * 1024),
          16, 0, 0);
    }
  };
  auto RS = [&](int ts) { return ts > NROWS - TROWS ? NROWS - TROWS : ts; };

  STAGE(0, RS(r0));
  __syncthreads();  // vmcnt(0) + barrier: tile 0 landed for all waves

  int buf = 0;
  for (int t = 0; t < nt; t++) {
    const int ts = r0 + t * TROWS;
    const int rs = RS(ts);
    if (t + 1 < nt) STAGE(buf ^ 1, RS(ts + TROWS));  // overlap with compute

    const int rend = (ts + TROWS < r1) ? ts + TROWS : r1;
    for (int r = ts; r < rend; r++) {
      // 2 distinct addresses per read (half 0/1) -> 2-way broadcast, free
      const f32x4* lp = (const f32x4*)&gt[buf][(r - rs) * DDIM + half * 64];
      float c0 = 0.f, c1 = 0.f, c2 = 0.f, c3 = 0.f;
#pragma unroll
      for (int j = 0; j < 16; j++) {
        const f32x4 g = lp[j];
        const f32x2 d0 = av[2 * j] - (f32x2){g.x, g.y};
        const f32x2 d1 = av[2 * j + 1] - (f32x2){g.z, g.w};
        c0 += fabsf(d0.x);  // v_add_f32 with |.| input modifier
        c1 += fabsf(d0.y);
        c2 += fabsf(d1.x);
        c3 += fabsf(d1.y);
      }
      const float p = (c0 + c1) + (c2 + c3);
      const float acc = p + __shfl_xor(p, 1, 64);  // pair-sum -> full distance
      if (acc < val[KK - 1]) topk_insert(val, idx, acc, r);
    }
    __syncthreads();  // drains vmcnt(0): prefetch landed; all waves done
    buf ^= 1;
  }

  // even lane of each pair writes its anchor's top-K
  // layout [chunk][k][dir*TT + a]: coalesced write AND coalesced merge read
  if ((lane & 1) == 0) {
    const int slot = dir * TT + a;
#pragma unroll
    for (int i = 0; i < KK; i++) {
      const size_t o = (size_t)(chunk * KK + i) * TT2 + slot;
      cand_val[o] = val[i];
      cand_idx[o] = idx[i];
    }
  }
}

// stage 1: merge groups of 8 chunks in place (16384 threads)
__global__ void merge1_kernel(float* __restrict__ cand_val,
                              int* __restrict__ cand_idx) {
  const int tid = blockIdx.x * blockDim.x + threadIdx.x;
  const int slot = tid & (TT2 - 1);  // consecutive tids -> coalesced
  const int part = tid >> 11;        // 0..7
  float val[KK];
  int idx[KK];
#pragma unroll
  for (int i = 0; i < KK; i++) {
    val[i] = 3.4e38f;
    idx[i] = 0;
  }
  // chunks ascending, k ascending: stable lowest-row-index tie order
  for (int q = 0; q < 8 * KK; q++) {
    const size_t o = (size_t)(part * 8 * KK + q) * TT2 + slot;
    const float v = cand_val[o];
    if (v < val[KK - 1]) topk_insert(val, idx, v, cand_idx[o]);
  }
#pragma unroll
  for (int i = 0; i < KK; i++) {
    const size_t o = (size_t)(part * 8 * KK + i) * TT2 + slot;
    cand_val[o] = val[i];
    cand_idx[o] = idx[i];
  }
}

// stage 2: merge the 8 compacted lists -> final negatives (2048 threads)
__global__ void merge2_kernel(const float* __restrict__ cand_val,
                              const int* __restrict__ cand_idx,
                              int* __restrict__ neg) {
  const int slot = blockIdx.x * blockDim.x + threadIdx.x;
  if (slot >= TT2) return;
  float val[KK];
  int idx[KK];
#pragma unroll
  for (int i = 0; i < KK; i++) {
    val[i] = 3.4e38f;
    idx[i] = 0;
  }
  for (int part = 0; part < 8; part++)
    for (int i = 0; i < KK; i++) {
      const size_t o = (size_t)(part * 8 * KK + i) * TT2 + slot;
      const float v = cand_val[o];
      if (v < val[KK - 1]) topk_insert(val, idx, v, cand_idx[o]);
    }
#pragma unroll
  for (int i = 0; i < KK; i++) neg[(size_t)slot * KK + i] = idx[i];
}

__global__ void zero_kernel(float* __restrict__ out) {
  if (threadIdx.x == 0) out[0] = 0.f;
}

__global__ void loss_kernel(const float* __restrict__ out1,
                            const float* __restrict__ out2,
                            const int* __restrict__ anc1,
                            const int* __restrict__ anc2,
                            const int* __restrict__ neg,  // [2][TT][KK]
                            float* __restrict__ out) {
  const int lane = threadIdx.x & 63;
  const int w = threadIdx.x >> 6;
  const int t = blockIdx.x * 4 + w;  // one wave per t
  const int a1 = anc1[t];
  const int a2 = anc2[t];
  const int e = lane * 2;  // 2 elements per lane

  const f32x2 x1 = *(const f32x2*)(out1 + (size_t)a1 * DDIM + e);
  const f32x2 x2 = *(const f32x2*)(out2 + (size_t)a2 * DDIM + e);

  float ap = fabsf(x1.x - x2.x) + fabsf(x1.y - x2.y);
#pragma unroll
  for (int o = 32; o > 0; o >>= 1) ap += __shfl_xor(ap, o, 64);
  const float Dm = ap + 1.0f;  // GAMMA = 1

  float s = 0.f;
  for (int k = 0; k < KK; k++) {
    const int n1 = neg[(size_t)t * KK + k];         // row of out2
    const int n2 = neg[(size_t)(TT + t) * KK + k];  // row of out1
    const f32x2 v1 = *(const f32x2*)(out2 + (size_t)n1 * DDIM + e);
    const f32x2 v2 = *(const f32x2*)(out1 + (size_t)n2 * DDIM + e);
    float d1 = fabsf(x1.x - v1.x) + fabsf(x1.y - v1.y);
    float d2 = fabsf(x2.x - v2.x) + fabsf(x2.y - v2.y);
#pragma unroll
    for (int o = 32; o > 0; o >>= 1) {
      d1 += __shfl_xor(d1, o, 64);
      d2 += __shfl_xor(d2, o, 64);
    }
    s += fmaxf(Dm - d1, 0.f) + fmaxf(Dm - d2, 0.f);
  }
  if (lane == 0) atomicAdd(out, s * (1.0f / (TT * KK)));
}

extern "C" void kernel_launch(void* const* d_in, const int* in_sizes, int n_in,
                              void* d_out, int out_size, void* d_ws,
                              size_t ws_size, hipStream_t stream) {
  const float* out1 = (const float*)d_in[0];
  const float* out2 = (const float*)d_in[1];
  const int* anc1 = (const int*)d_in[2];
  const int* anc2 = (const int*)d_in[3];

  // workspace: cand_val (5.24MB) | cand_idx (5.24MB) | neg (80KB)  ~= 10.6MB
  float* cand_val = (float*)d_ws;
  int* cand_idx = (int*)(cand_val + (size_t)NCH * KK * TT2);
  int* neg = cand_idx + (size_t)NCH * KK * TT2;
  float* out = (float*)d_out;

  hipLaunchKernelGGL(mine_kernel, dim3(1024), dim3(256), 0, stream, out1, out2,
                     anc1, anc2, cand_val, cand_idx);
  hipLaunchKernelGGL(merge1_kernel, dim3(64), dim3(256), 0, stream, cand_val,
                     cand_idx);
  hipLaunchKernelGGL(merge2_kernel, dim3(8), dim3(256), 0, stream, cand_val,
                     cand_idx, neg);
  hipLaunchKernelGGL(zero_kernel, dim3(1), dim3(64), 0, stream, out);
  hipLaunchKernelGGL(loss_kernel, dim3(TT / 4), dim3(256), 0, stream, out1,
                     out2, anc1, anc2, neg, out);
}